// Round 1
// 93.266 us; speedup vs baseline: 1.2666x; 1.2666x over previous
//
#include <hip/hip_runtime.h>

// GAT forward, O(N*HD) via sorted-prefix decomposition. B=8,N=1024,F=128,H=4,HD=32.
// score(i,j)=s_i+d_j; negative iff d_j < -s_i. Per (b,h), sort j by d_j:
//   out[i,:] = (c2*PB[k_i] + c1*SufA[k_i]) / (c2*PBs[k_i] + c1*SufAs[k_i])
// PB: exclusive prefix of e^{0.2d}*h; SufA: inclusive suffix of e^{d}*h;
// k_i = lower_bound(dsrt, -s_i); c1=e^s, c2=e^{0.2s}.
//
// R1 restructure:
//  K1 proj: s/d computed from acc[] via __shfl_xor cross-lane reduce (exact),
//           removing 128 scattered W loads/thread and the doSD hot-loop work.
//  Tail split by parallelism class (old fused tail: 32 blocks, 3.7% occupancy):
//   K2 sort  (32 x 1024): bitonic sort only -> dsrt, pj.
//   K3 scan  (256 x 256, full chip): per block = (bh, 4 chunks) x {fwd,bwd};
//            32-long serial scans, writes tbl + scalar prefixes + chunk totals.
//   K4 out   (128 x 256): per block = (bh, 256 rows); rebuilds 33x32 chunk
//            offsets in LDS (cheap), then search + gather + combine.
//  bh = blockIdx&31 keeps each bh's blocks on one XCD (round-robin %8 heuristic)
//  so tbl/dsrt stay L2-local between K2/K3/K4.

constexpr int CB  = 8;
constexpr int CN  = 1024;
constexpr int CF  = 128;
constexpr int CH  = 4;
constexpr int CHD = 32;
constexpr int CBH = CB * CH;        // 32
constexpr int CROWS = CB * CN;      // 8192
constexpr int TROWS = CN + 1;       // 1025 table rows (row 1024 = zeros)

// ---------------- K1: projection + exact s/d ----------------
// 512 blocks x 256 thr; block = 16 rows x 128 cols; thread = (row=tid&15, g=tid>>4)
// owning 8 cols. x in LDS stride-132 (2-way max = free); W in LDS 64-k slabs
// (broadcast reads). s/d: per-thread partial dot of acc[8] with a_src/a_dst,
// reduced across the 4 g-threads of the head via shfl_xor(16) + shfl_xor(32).
__global__ __launch_bounds__(256) void proj_kernel(
    const float* __restrict__ x, const float* __restrict__ W,
    const float* __restrict__ a_src, const float* __restrict__ a_dst,
    float* __restrict__ h_ws, float* __restrict__ sarr, float* __restrict__ darr)
{
    __shared__ float xs[16 * 132];      // 8.4 KB, padded stride
    __shared__ float wslab[64 * 128];   // 32 KB

    const int tid = threadIdx.x, row0 = blockIdx.x * 16;

    // stage x tile: 512 float4, coalesced; padded LDS write
    const float4* x4 = (const float4*)x;
    #pragma unroll
    for (int m = 0; m < 2; ++m) {
        const int idx = m * 256 + tid;              // 0..511
        const int r = idx >> 5, k4 = idx & 31;
        *(float4*)(xs + r * 132 + k4 * 4) = x4[(size_t)row0 * 32 + idx];
    }

    const int row = tid & 15, g = tid >> 4;         // g: 16 col-groups of 8
    const int head = g >> 2, dd0 = (g & 3) * 8;
    float acc[8] = {0.f,0.f,0.f,0.f,0.f,0.f,0.f,0.f};

    const float4* W4 = (const float4*)W;
    for (int slab = 0; slab < 2; ++slab) {
        __syncthreads();                            // xs ready; wslab free to overwrite
        #pragma unroll
        for (int m = 0; m < 8; ++m) {
            const int idx = m * 256 + tid;          // 0..2047
            const int kk = idx >> 5, k4 = idx & 31;
            *(float4*)(wslab + kk * 128 + k4 * 4) = W4[(size_t)(slab * 64 + kk) * 32 + k4];
        }
        __syncthreads();
        #pragma unroll 4
        for (int k4 = 0; k4 < 16; ++k4) {
            const float4 xv = *(const float4*)(xs + row * 132 + slab * 64 + k4 * 4);
            const float xq[4] = {xv.x, xv.y, xv.z, xv.w};
            #pragma unroll
            for (int q = 0; q < 4; ++q) {
                const int kk = k4 * 4 + q;
                const float4 wa = *(const float4*)(wslab + kk * 128 + g * 8);
                const float4 wb = *(const float4*)(wslab + kk * 128 + g * 8 + 4);
                const float xk = xq[q];
                acc[0] += xk * wa.x; acc[1] += xk * wa.y;
                acc[2] += xk * wa.z; acc[3] += xk * wa.w;
                acc[4] += xk * wb.x; acc[5] += xk * wb.y;
                acc[6] += xk * wb.z; acc[7] += xk * wb.w;
            }
        }
    }

    // s/d from accumulators: dot over this thread's 8 dd, reduce over 4 g-threads.
    const float4 as0 = *(const float4*)(a_src + head * CHD + dd0);
    const float4 as1 = *(const float4*)(a_src + head * CHD + dd0 + 4);
    const float4 ad0 = *(const float4*)(a_dst + head * CHD + dd0);
    const float4 ad1 = *(const float4*)(a_dst + head * CHD + dd0 + 4);
    float sp = acc[0]*as0.x + acc[1]*as0.y + acc[2]*as0.z + acc[3]*as0.w
             + acc[4]*as1.x + acc[5]*as1.y + acc[6]*as1.z + acc[7]*as1.w;
    float dp = acc[0]*ad0.x + acc[1]*ad0.y + acc[2]*ad0.z + acc[3]*ad0.w
             + acc[4]*ad1.x + acc[5]*ad1.y + acc[6]*ad1.z + acc[7]*ad1.w;
    // gi-threads of a head sit 16 and 32 lanes apart within the wave
    sp += __shfl_xor(sp, 16); sp += __shfl_xor(sp, 32);
    dp += __shfl_xor(dp, 16); dp += __shfl_xor(dp, 32);

    const int rowg = row0 + row, b = rowg >> 10, n = rowg & 1023;
    const int bh = b * CH + head;
    float* hp = h_ws + (size_t)(bh * CN + n) * CHD + dd0;
    *(float4*)hp       = make_float4(acc[0], acc[1], acc[2], acc[3]);
    *(float4*)(hp + 4) = make_float4(acc[4], acc[5], acc[6], acc[7]);
    if ((g & 3) == 0) {
        sarr[bh * CN + n] = sp;
        darr[bh * CN + n] = dp;
    }
}

// ---------------- K2: bitonic sort per bh ----------------
// 32 blocks x 1024 thr. (d,p) lex order; regs + shuffles j<64, LDS j>=64.
__global__ __launch_bounds__(1024) void sort_kernel(
    const float* __restrict__ darr, float* __restrict__ dsrt_g,
    int* __restrict__ pj_g, float* __restrict__ sPB_g, float* __restrict__ sSF_g,
    float* __restrict__ tbl_g)
{
    __shared__ float dsS[CN];
    __shared__ int   pjS[CN];
    const int bh = blockIdx.x, tid = threadIdx.x;

    float d = darr[bh * CN + tid];
    int   p = tid;
    for (int k = 2; k <= CN; k <<= 1) {
        for (int j = k >> 1; j > 0; j >>= 1) {
            float pd; int pp;
            if (j >= 64) {
                dsS[tid] = d; pjS[tid] = p;
                __syncthreads();
                pd = dsS[tid ^ j]; pp = pjS[tid ^ j];
                __syncthreads();
            } else {
                pd = __shfl_xor(d, j);
                pp = __shfl_xor(p, j);
            }
            const bool up = ((tid & k) == 0), low = ((tid & j) == 0);
            const bool mg = (d > pd) || (d == pd && p > pp);
            if (mg == (low == up)) { d = pd; p = pp; }
        }
    }
    dsrt_g[bh * CN + tid] = d;
    pj_g[bh * CN + tid]   = p;
    if (tid < 64) tbl_g[(size_t)bh * TROWS * 64 + (size_t)CN * 64 + tid] = 0.f;  // virtual row
    if (tid == 0) { sPB_g[bh * TROWS + CN] = 0.f; sSF_g[bh * TROWS + CN] = 0.f; }
}

// ---------------- K3: chunk-local scans ----------------
// 256 blocks x 256 thr: block = (bh = idx&31, cg = idx>>5) covering chunks
// cg*4..cg*4+3. Thread = (dir=tid>>7, cidx=(tid>>5)&3, dd=tid&31).
// fwd: exclusive prefix of e^{0.2d}*h; bwd: inclusive suffix of e^{d}*h.
__global__ __launch_bounds__(256) void scan_kernel(
    const float* __restrict__ h_ws, const float* __restrict__ dsrt_g,
    const int* __restrict__ pj_g, float* __restrict__ tbl_g,
    float* __restrict__ sPB_g, float* __restrict__ sSF_g,
    float* __restrict__ ctF_g, float* __restrict__ ctB_g,
    float* __restrict__ ctSF_g, float* __restrict__ ctSB_g)
{
    __shared__ float dch[128];
    __shared__ int   pch[128];
    const int bh = blockIdx.x & 31, cg = blockIdx.x >> 5;
    const int tid = threadIdx.x, base = cg * 128;

    if (tid < 128) dch[tid] = dsrt_g[bh * CN + base + tid];
    else           pch[tid - 128] = pj_g[bh * CN + base + (tid - 128)];
    __syncthreads();

    const int dir = tid >> 7, cidx = (tid >> 5) & 3, dd = tid & 31;
    const int c = cg * 4 + cidx, lb = cidx * 32;
    const float* hb = h_ws + (size_t)bh * CN * CHD;
    float* tbl = tbl_g + (size_t)bh * TROWS * 64;

    if (dir == 0) {   // forward
        float accF = 0.f, accS = 0.f;
        for (int bt = 0; bt < 2; ++bt) {
            float hv[16], dv[16];
            #pragma unroll
            for (int t = 0; t < 16; ++t) {
                const int lp = lb + bt * 16 + t;
                hv[t] = hb[(size_t)pch[lp] * CHD + dd];
                dv[t] = dch[lp];
            }
            #pragma unroll
            for (int t = 0; t < 16; ++t) {
                const int pos = base + lb + bt * 16 + t;
                const float cf = __expf(0.2f * dv[t]);
                tbl[pos * 64 + dd] = accF;
                if (dd == 0) sPB_g[bh * TROWS + pos] = accS;
                accF += cf * hv[t];
                accS += cf;
            }
        }
        ctF_g[(bh * 32 + c) * 32 + dd] = accF;
        if (dd == 0) ctSF_g[bh * 32 + c] = accS;
    } else {          // backward
        float accB = 0.f, accS = 0.f;
        for (int bt = 0; bt < 2; ++bt) {
            float hv[16], dv[16];
            #pragma unroll
            for (int t = 0; t < 16; ++t) {
                const int lp = lb + 31 - (bt * 16 + t);
                hv[t] = hb[(size_t)pch[lp] * CHD + dd];
                dv[t] = dch[lp];
            }
            #pragma unroll
            for (int t = 0; t < 16; ++t) {
                const int pos = base + lb + 31 - (bt * 16 + t);
                const float cf = __expf(dv[t]);
                accB += cf * hv[t];
                accS += cf;
                tbl[pos * 64 + 32 + dd] = accB;
                if (dd == 0) sSF_g[bh * TROWS + pos] = accS;
            }
        }
        ctB_g[(bh * 32 + c) * 32 + dd] = accB;
        if (dd == 0) ctSB_g[bh * 32 + c] = accS;
    }
}

// ---------------- K4: per-row search + gather + combine ----------------
// 128 blocks x 256 thr: block = (bh = idx&31, q = idx>>5) handling rows
// q*256..q*256+255. Chunk offsets rebuilt in LDS (64+2 threads, serial 32).
__global__ __launch_bounds__(256) void out_kernel(
    const float* __restrict__ sarr, const float* __restrict__ dsrt_g,
    const float* __restrict__ sPB_g, const float* __restrict__ sSF_g,
    const float* __restrict__ ctF_g, const float* __restrict__ ctB_g,
    const float* __restrict__ ctSF_g, const float* __restrict__ ctSB_g,
    const float* __restrict__ tbl_g, float* __restrict__ out)
{
    __shared__ float dsS[CN];              // sorted d (binary search)
    __shared__ float ctF[32 * 32], ctB[32 * 32];
    __shared__ float ctSF[32], ctSB[32];
    __shared__ float ofF[33 * 32], ofB[33 * 32];
    __shared__ float ofSF[33], ofSB[33];

    const int bh = blockIdx.x & 31, q = blockIdx.x >> 5;
    const int tid = threadIdx.x;

    #pragma unroll
    for (int r = 0; r < 4; ++r) {
        const int idx = r * 256 + tid;
        dsS[idx] = dsrt_g[bh * CN + idx];
        ctF[idx] = ctF_g[bh * 1024 + idx];
        ctB[idx] = ctB_g[bh * 1024 + idx];
    }
    if (tid < 32)       ctSF[tid] = ctSF_g[bh * 32 + tid];
    else if (tid < 64)  ctSB[tid - 32] = ctSB_g[bh * 32 + (tid - 32)];
    __syncthreads();

    if (tid < 32) {                  // fwd vector offsets, dd = tid
        float run = 0.f;
        for (int c = 0; c < 32; ++c) { ofF[c * 32 + tid] = run; run += ctF[c * 32 + tid]; }
        ofF[32 * 32 + tid] = run;
    } else if (tid < 64) {           // bwd vector offsets
        const int dd = tid - 32;
        float run = 0.f;
        ofB[32 * 32 + dd] = 0.f;
        for (int c = 31; c >= 0; --c) { ofB[c * 32 + dd] = run; run += ctB[c * 32 + dd]; }
    } else if (tid == 64) {          // fwd scalar offsets
        float run = 0.f;
        for (int c = 0; c < 32; ++c) { ofSF[c] = run; run += ctSF[c]; }
        ofSF[32] = run;
    } else if (tid == 65) {          // bwd scalar offsets
        float run = 0.f;
        ofSB[32] = 0.f;
        for (int c = 31; c >= 0; --c) { ofSB[c] = run; run += ctSB[c]; }
    }
    __syncthreads();

    const int i = q * 256 + tid;
    const float s = sarr[bh * CN + i];
    const float c1 = __expf(s), c2v = __expf(0.2f * s), thr = -s;
    int lo = 0, hi = CN;
    while (lo < hi) { const int mid = (lo + hi) >> 1; if (dsS[mid] < thr) lo = mid + 1; else hi = mid; }
    const int k = lo, kc = k >> 5;               // 0..32 (k==1024 -> 32)

    const float PBs = sPB_g[bh * TROWS + k] + ofSF[kc];
    const float SFs = sSF_g[bh * TROWS + k] + ofSB[kc];
    const float inv = 1.0f / (c2v * PBs + c1 * SFs);

    const float4* tr = (const float4*)(tbl_g + (size_t)bh * TROWS * 64 + (size_t)k * 64);
    const int b = bh >> 2, hh = bh & 3;
    float4* o = (float4*)(out + (size_t)(b * CN + i) * CF + hh * 32);
    #pragma unroll
    for (int qq = 0; qq < 8; ++qq) {
        const float4 pb = tr[qq], sf = tr[8 + qq];
        const float4 oa = *(const float4*)(&ofF[kc * 32 + qq * 4]);
        const float4 ob = *(const float4*)(&ofB[kc * 32 + qq * 4]);
        float4 r;
        r.x = (c2v * (pb.x + oa.x) + c1 * (sf.x + ob.x)) * inv;
        r.y = (c2v * (pb.y + oa.y) + c1 * (sf.y + ob.y)) * inv;
        r.z = (c2v * (pb.z + oa.z) + c1 * (sf.z + ob.z)) * inv;
        r.w = (c2v * (pb.w + oa.w) + c1 * (sf.w + ob.w)) * inv;
        o[qq] = r;
    }
}

extern "C" void kernel_launch(void* const* d_in, const int* in_sizes, int n_in,
                              void* d_out, int out_size, void* d_ws, size_t ws_size,
                              hipStream_t stream) {
    const float* x     = (const float*)d_in[0];
    const float* W     = (const float*)d_in[1];
    const float* a_src = (const float*)d_in[2];
    const float* a_dst = (const float*)d_in[3];
    float* out = (float*)d_out;

    char* ws = (char*)d_ws;
    size_t off = 0;
    float* h_ws = (float*)(ws + off); off += (size_t)CROWS * CF * 4;          // 4 MB
    float* sarr = (float*)(ws + off); off += (size_t)CBH * CN * 4;            // 128 KB
    float* darr = (float*)(ws + off); off += (size_t)CBH * CN * 4;            // 128 KB
    float* tblg = (float*)(ws + off); off += (size_t)CBH * TROWS * 64 * 4;    // 8.4 MB
    float* dsrt = (float*)(ws + off); off += (size_t)CBH * CN * 4;            // 128 KB
    int*   pjg  = (int*)  (ws + off); off += (size_t)CBH * CN * 4;            // 128 KB
    float* sPBg = (float*)(ws + off); off += (size_t)CBH * TROWS * 4;         // 131 KB
    float* sSFg = (float*)(ws + off); off += (size_t)CBH * TROWS * 4;         // 131 KB
    float* ctFg = (float*)(ws + off); off += (size_t)CBH * 32 * 32 * 4;       // 128 KB
    float* ctBg = (float*)(ws + off); off += (size_t)CBH * 32 * 32 * 4;       // 128 KB
    float* ctSFg= (float*)(ws + off); off += (size_t)CBH * 32 * 4;            // 4 KB
    float* ctSBg= (float*)(ws + off); off += (size_t)CBH * 32 * 4;            // 4 KB
    (void)ws_size;

    proj_kernel<<<CROWS / 16, 256, 0, stream>>>(x, W, a_src, a_dst, h_ws, sarr, darr);
    sort_kernel<<<CBH, 1024, 0, stream>>>(darr, dsrt, pjg, sPBg, sSFg, tblg);
    scan_kernel<<<256, 256, 0, stream>>>(h_ws, dsrt, pjg, tblg, sPBg, sSFg,
                                         ctFg, ctBg, ctSFg, ctSBg);
    out_kernel<<<128, 256, 0, stream>>>(sarr, dsrt, sPBg, sSFg,
                                        ctFg, ctBg, ctSFg, ctSBg, tblg, out);
}